// Round 18
// baseline (4819.291 us; speedup 1.0000x reference)
//
#include <hip/hip_runtime.h>
#include <hip/hip_bf16.h>
#include <stdint.h>

typedef unsigned short ushort_t;
typedef unsigned char u8_t;
typedef unsigned long long u64_t;

#define H   512
#define E   128
#define NC  27
#define NE  28
#define B   256
#define T   512
#define FH  2048        // 4*H
#define NPH (T + 2)     // phases 0..T+1
#define NL0 64
#define NL1 128
#define NOUT 32
#define BHs (B * H)
#define WOFF 65536      // L0: ring 8x8KB + 64KB weights; L1: ring 8x8KB + 96KB weights
#define LDS_BYTES (160 * 1024)
#define CROW 256        // ints per role-phase row (16 cells x 16-int stride)

typedef __bf16 bf16x8 __attribute__((ext_vector_type(8)));
typedef float  f32x4  __attribute__((ext_vector_type(4)));

#define WAITV(n) asm volatile("s_waitcnt vmcnt(" #n ")" ::: "memory")
#define LADDER8(rem) do { if ((rem) >= 7) WAITV(7); else if ((rem) == 6) WAITV(6); \
                          else if ((rem) == 5) WAITV(5); else if ((rem) == 4) WAITV(4); \
                          else if ((rem) == 3) WAITV(3); else if ((rem) == 2) WAITV(2); \
                          else if ((rem) == 1) WAITV(1); else WAITV(0); } while (0)

__device__ __forceinline__ ushort_t f2b(float x) {
    uint32_t u = __float_as_uint(x);
    uint32_t r = (u + 0x7FFFu + ((u >> 16) & 1u)) >> 16;
    return (ushort_t)r;
}
// f32 -> fp8 e4m3fn, RNE, handles subnormals
__device__ __forceinline__ u8_t f2fp8(float x) {
    uint32_t u = __float_as_uint(x);
    uint32_t s = (u >> 24) & 0x80u;
    int E8 = (int)((u >> 23) & 0xffu);
    uint32_t M = u & 0x7fffffu;
    if (E8 == 0) return (u8_t)s;
    int e8 = E8 - 120;
    uint32_t code;
    if (e8 <= 0) {
        int sh = 1 - e8;
        if (sh > 23) return (u8_t)s;
        code = (0x800000u | M) >> sh;
    } else {
        code = ((uint32_t)e8 << 23) | M;
    }
    uint32_t r = (code + 0x7ffffu + ((code >> 20) & 1u)) >> 20;
    if (r > 0x7eu) r = 0x7eu;
    return (u8_t)(s | r);
}
__device__ __forceinline__ float sigm(float x) {
    return 1.f / (1.f + __expf(-x));
}
__device__ __forceinline__ void stc1(u8_t* p, u8_t v) {
    __hip_atomic_store(p, v, __ATOMIC_RELAXED, __HIP_MEMORY_SCOPE_AGENT);
}
__device__ __forceinline__ void stc2(ushort_t* p, ushort_t v) {
    __hip_atomic_store(p, v, __ATOMIC_RELAXED, __HIP_MEMORY_SCOPE_AGENT);
}
__device__ __forceinline__ void stc4f(float* p, float v) {
    __hip_atomic_store(p, v, __ATOMIC_RELAXED, __HIP_MEMORY_SCOPE_AGENT);
}
__device__ __forceinline__ bf16x8 ldc16(const ushort_t* p) {
    union { u64_t q[2]; bf16x8 v; } u;
    u.q[0] = __hip_atomic_load((const u64_t*)p,       __ATOMIC_RELAXED, __HIP_MEMORY_SCOPE_AGENT);
    u.q[1] = __hip_atomic_load(((const u64_t*)p) + 1, __ATOMIC_RELAXED, __HIP_MEMORY_SCOPE_AGENT);
    return u.v;
}
__device__ __forceinline__ void gload_lds16c(const void* g, void* l) {
    __builtin_amdgcn_global_load_lds(
        (const __attribute__((address_space(1))) void*)g,
        (__attribute__((address_space(3))) void*)l, 16, 0, 17);
}

// stage one fp8 A-chunk [128 rows][64 cols] = 8 KB (wave strip = 16 rows)
__device__ __forceinline__ void stageB8(const u8_t* __restrict__ hsrc, int rb, int k0,
                                        char* chunk, int wave, int lane) {
    int r = wave * 16 + (lane >> 2);
    int gd = lane & 3;
    int fr = (r & 3) ^ ((r >> 2) & 3);
    const u8_t* g = hsrc + (size_t)(rb + r) * H + k0 + ((gd ^ fr) << 4);
    gload_lds16c((const void*)g, (void*)(chunk + wave * 1024));
}

// ---------------- setup kernels ----------------

__global__ void k_init(int* __restrict__ cnt) {
    for (int i = blockIdx.x * blockDim.x + threadIdx.x; i < 3 * NPH * CROW;
         i += gridDim.x * blockDim.x) cnt[i] = 0;
}

// G0 layout: [cell][token][j][gate] f32
__global__ void k_g0(const float* __restrict__ embed, const float* __restrict__ Wih0,
                     const float* __restrict__ bih, const float* __restrict__ bhh,
                     float* __restrict__ G0, float* __restrict__ bias1) {
    int i = blockIdx.x * blockDim.x + threadIdx.x;
    if (i < 2 * NE * FH) {
        int d = i / (NE * FH);
        int rem = i % (NE * FH);
        int e = rem / FH;
        int n = rem % FH;
        int g = n >> 9, j = n & 511;
        const float* er = embed + (size_t)e * E;
        const float* wr = Wih0 + ((size_t)d * FH + n) * E;
        float s = 0.f;
        #pragma unroll 8
        for (int k = 0; k < E; ++k) s += er[k] * wr[k];
        G0[(((size_t)d * NE + e) * 512 + j) * 4 + g]
            = s + bih[(size_t)d * FH + n] + bhh[(size_t)d * FH + n];
    }
    if (i < 2 * FH) bias1[i] = bih[2 * FH + i] + bhh[2 * FH + i];
}

// initial h = step -1 -> parity 2
__global__ void k_state(const float* __restrict__ h0, ushort_t* __restrict__ hb16,
                        u8_t* __restrict__ hf8) {
    int i = blockIdx.x * blockDim.x + threadIdx.x;
    if (i >= 4 * B * H) return;
    int cell = i / (B * H);
    int rem  = i % (B * H);
    hb16[((size_t)(cell * 3 + 2)) * BHs + rem] = f2b(h0[i]);
    hf8 [((size_t)(cell * 3 + 2)) * BHs + rem] = f2fp8(h0[i]);
}

__global__ void k_tokT(const int* __restrict__ tok, int* __restrict__ tokT) {
    int i = blockIdx.x * blockDim.x + threadIdx.x;
    if (i < B * T) {
        int b = i / T, t = i % T;
        tokT[(size_t)t * B + b] = tok[i];
    }
}

__global__ void k_len(const int* __restrict__ lens, float* __restrict__ out_len) {
    int i = threadIdx.x;
    if (i < B) out_len[i] = (float)lens[i];
}

// ---------------- decoupled role sync (decontended lines) ----------------
__device__ __forceinline__ int polled(const int* c) {
    int t = 0;
    #pragma unroll
    for (int i = 0; i < 16; ++i)
        t += __hip_atomic_load(c + i * 16, __ATOMIC_RELAXED, __HIP_MEMORY_SCOPE_AGENT);
    return t;
}

// boundary: signal phase p; poll deps of phase q=p+1 needed AT PHASE START.
__device__ __forceinline__ void boundary(int* cntL0, int* cntL1, int* cntOUT,
                                         int role, int bid, int p) {
    __syncthreads();                          // drain this block's vmem (h-stores)
    if (threadIdx.x == 0) {
        int* mine = (role == 0) ? cntL0 : (role == 1) ? cntL1 : cntOUT;
        __hip_atomic_fetch_add(mine + p * CROW + (bid & 15) * 16, 1,
                               __ATOMIC_RELAXED, __HIP_MEMORY_SCOPE_AGENT);
        const int q = p + 1;
        int nl0 = -1, nl1 = -1;
        if (role == 0) {
            if (q < T) {
                nl0 = q - 1;
                if (q >= 2) nl1 = q - 2;
            }
        } else if (role == 1) {
            if (q >= 1 && q <= T) nl0 = q - 1;
        } else {
            if (q >= 2) nl1 = q - 1;
        }
        for (;;) {
            int a = (nl0 >= 0) ? polled(cntL0 + nl0 * CROW) : NL0;
            int b = (nl1 >= 0) ? polled(cntL1 + nl1 * CROW) : NL1;
            if (a >= NL0 && b >= NL1) break;
            __builtin_amdgcn_s_sleep(2);
        }
    }
    __syncthreads();
    __builtin_amdgcn_sched_barrier(0);
}

// deferred L1 gate (mid-phase, after y0 segment): L1[p-1] ∧ OUT[p-2].
__device__ __forceinline__ void gateL1(const int* cntL1, const int* cntOUT, int p) {
    __builtin_amdgcn_sched_barrier(0);
    if (threadIdx.x == 0) {
        for (;;) {
            int a = polled(cntL1 + (p - 1) * CROW);
            int b = (p >= 2) ? polled(cntOUT + (p - 2) * CROW) : NOUT;
            if (a >= NL1 && b >= NOUT) break;
            __builtin_amdgcn_s_sleep(2);
        }
    }
    __builtin_amdgcn_s_barrier();
    __builtin_amdgcn_sched_barrier(0);
}

// Phase p: L0 step t=p (p<T); L1 step s=p-1 (1<=p<=T); OUT logits t2=p-2 (p>=2).
// hf8/hb16: [cell][3][B][H]; step s lives at parity s%3.
__global__ __launch_bounds__(512, 2) void k_persist(
    const float* __restrict__ Whh, const float* __restrict__ Wih1,
    const float* __restrict__ G0, const float* __restrict__ bias1,
    const float* __restrict__ c0, ushort_t* __restrict__ hb16,
    u8_t* __restrict__ hf8,
    const int* __restrict__ tokT, const int* __restrict__ lens,
    const float* __restrict__ Wout, const float* __restrict__ bout,
    float* __restrict__ out, int* __restrict__ cnt)
{
    extern __shared__ char smem[];
    const int bid = blockIdx.x;
    const int tid = threadIdx.x;
    const int lane = tid & 63, wave = tid >> 6;
    const int lrow = lane & 15, kg = lane >> 4;
    const int sw8 = lrow & 7;

    int* cntL0  = cnt;
    int* cntL1  = cnt + NPH * CROW;
    int* cntOUT = cnt + 2 * NPH * CROW;
    const int role = (bid < NL0) ? 0 : (bid < NL0 + NL1) ? 1 : 2;

    int wksoff[2];
    #pragma unroll
    for (int ks = 0; ks < 2; ++ks)
        wksoff[ks] = (((ks * 4 + kg) ^ sw8) << 3);
    // A-read offsets for [128][64] fp8 chunks (matches stageB8 source swizzle)
    const int fB = (lrow & 3) ^ ((wave * 4 + (lrow >> 2)) & 3);
    int aoffB[2];
    #pragma unroll
    for (int ks = 0; ks < 2; ++ks)
        aoffB[ks] = (wave * 16 + lrow) * 64 + ((((ks << 1) | (kg >> 1)) ^ fB) << 4) + ((kg & 1) << 3);

    // ---- one-time: stage weights into LDS (f32 -> fp8, slot-swizzled) ----
    if (bid < 64) {
        // L0: 128 weight rows (4 gates x 32 j), K=512
        const int cell = bid >> 5, rem0 = bid & 31, jt = rem0 & 15, j0 = jt * 32;
        const float* Wsrc = Whh + (size_t)cell * FH * H;
        for (int r = wave; r < 128; r += 8) {
            int grow = (r >> 5) * 512 + j0 + (r & 31);
            const float* src = Wsrc + (size_t)grow * H;
            for (int c = lane; c < H; c += 64) {
                int slot = c >> 3;
                int ssw = (slot & ~7) | ((slot ^ r) & 7);
                *(u8_t*)(smem + WOFF + r * 512 + ssw * 8 + (c & 7)) = f2fp8(src[c]);
            }
        }
    } else if (bid < 192) {
        const int q = bid - 64;
        const int rem = q & 63, cell = 2 + (rem >> 5), jt = rem & 31, j0 = jt * 16;
        const float* Wi = Wih1 + (size_t)(cell - 2) * FH * (2 * H);
        const float* Wh = Whh + (size_t)cell * FH * H;
        for (int r = wave; r < 64; r += 8) {
            int grow = (r >> 4) * 512 + j0 + (r & 15);
            const float* si = Wi + (size_t)grow * (2 * H);
            const float* sh = Wh + (size_t)grow * H;
            for (int c = lane; c < 1536; c += 64) {
                float v = (c < 1024) ? si[c] : sh[c - 1024];
                int slot = c >> 3;
                int ssw = (slot & ~7) | ((slot ^ r) & 7);
                *(u8_t*)(smem + WOFF + r * 1536 + ssw * 8 + (c & 7)) = f2fp8(v);
            }
        }
    } else {
        for (int r = wave; r < NC; r += 8) {
            const float* src = Wout + (size_t)r * (2 * H);
            int sw = (r & 7) << 4;
            for (int c = lane; c < 2 * H; c += 64) {
                int byte = ((r * (2 * H) + c) * 2) ^ sw;
                *(ushort_t*)(smem + byte) = f2b(src[c]);
            }
        }
    }
    __syncthreads();

    if (bid < 64) {
        // ===== layer 0 (fp8, 2-D tile: 32 j x 128 batch rows) =====
        const int cell = bid >> 5, rem0 = bid & 31;
        const int bt = rem0 >> 4, jt = rem0 & 15;
        const int j0 = jt * 32, rb = bt * 128;
        int wgbase[4][2];
        #pragma unroll
        for (int g = 0; g < 4; ++g)
            #pragma unroll
            for (int jf = 0; jf < 2; ++jf)
                wgbase[g][jf] = WOFF + (g * 32 + jf * 16 + lrow) * 512;

        float cv[8];            // [jf][r]
        #pragma unroll
        for (int jf = 0; jf < 2; ++jf)
            #pragma unroll
            for (int r = 0; r < 4; ++r) {
                int bb = rb + wave * 16 + kg * 4 + r;
                int j2 = j0 + jf * 16 + lrow;
                cv[jf * 4 + r] = c0[((size_t)cell * B + bb) * H + j2];
            }
        f32x4 g0v[8];           // [jf][r]
        #pragma unroll
        for (int jf = 0; jf < 2; ++jf)
            #pragma unroll
            for (int r = 0; r < 4; ++r) {
                int bb = rb + wave * 16 + kg * 4 + r;
                int tk = tokT[bb];
                int j2 = j0 + jf * 16 + lrow;
                g0v[jf * 4 + r] = *(const f32x4*)(G0 + (((size_t)cell * NE + tk) * 512 + j2) * 4);
            }

        for (int p = 0; p < NPH; ++p) {
            if (p < T) {
                const int pm3 = p % 3;
                const int parR = (pm3 + 2) % 3, parW = pm3;
                const u8_t* hsrc = hf8 + (size_t)(cell * 3 + parR) * BHs;

                #pragma unroll
                for (int c2 = 0; c2 < 8; ++c2)
                    stageB8(hsrc, rb, c2 * 64, smem + c2 * 8192, wave, lane);

                f32x4 acc[4][2];
                #pragma unroll
                for (int g = 0; g < 4; ++g)
                    #pragma unroll
                    for (int jf = 0; jf < 2; ++jf) acc[g][jf] = (f32x4){0.f, 0.f, 0.f, 0.f};

                #pragma unroll
                for (int t = 0; t < 8; ++t) {
                    LADDER8(7 - t);
                    __builtin_amdgcn_sched_barrier(0);
                    const char* Ab = smem + t * 8192;
                    u64_t aA[2], wW[2][4][2];
                    #pragma unroll
                    for (int ks = 0; ks < 2; ++ks) {
                        aA[ks] = *(const u64_t*)(Ab + aoffB[ks]);
                        #pragma unroll
                        for (int g = 0; g < 4; ++g)
                            #pragma unroll
                            for (int jf = 0; jf < 2; ++jf)
                                wW[ks][g][jf] = *(const u64_t*)(smem + wgbase[g][jf] + t * 64 + wksoff[ks]);
                    }
                    asm volatile("s_waitcnt lgkmcnt(0)" ::: "memory");
                    __builtin_amdgcn_sched_barrier(0);
                    #pragma unroll
                    for (int ks = 0; ks < 2; ++ks)
                        #pragma unroll
                        for (int g = 0; g < 4; ++g)
                            #pragma unroll
                            for (int jf = 0; jf < 2; ++jf)
                                acc[g][jf] = __builtin_amdgcn_mfma_f32_16x16x32_fp8_fp8(
                                    (long)aA[ks], (long)wW[ks][g][jf], acc[g][jf], 0, 0, 0);
                }

                #pragma unroll
                for (int jf = 0; jf < 2; ++jf) {
                    int j2 = j0 + jf * 16 + lrow;
                    #pragma unroll
                    for (int r = 0; r < 4; ++r) {
                        int bb = rb + wave * 16 + kg * 4 + r;
                        f32x4 gq = g0v[jf * 4 + r];
                        float gi = acc[0][jf][r] + gq[0];
                        float gf = acc[1][jf][r] + gq[1];
                        float gg = acc[2][jf][r] + gq[2];
                        float go = acc[3][jf][r] + gq[3];
                        float ii = sigm(gi), ff = sigm(gf), oo = sigm(go);
                        float tg = tanhf(gg);
                        int ci = jf * 4 + r;
                        float cn = ff * cv[ci] + ii * tg;
                        cv[ci] = cn;
                        float hn = oo * tanhf(cn);
                        stc1(&hf8[((size_t)(cell * 3 + parW) * B + bb) * H + j2], f2fp8(hn));
                    }
                }
                if (p + 1 < T) {
                    #pragma unroll
                    for (int jf = 0; jf < 2; ++jf)
                        #pragma unroll
                        for (int r = 0; r < 4; ++r) {
                            int bb = rb + wave * 16 + kg * 4 + r;
                            int tk = tokT[(size_t)(p + 1) * B + bb];
                            int j2 = j0 + jf * 16 + lrow;
                            g0v[jf * 4 + r] = *(const f32x4*)(G0 + (((size_t)cell * NE + tk) * 512 + j2) * 4);
                        }
                }
            }
            if (p < NPH - 1) boundary(cntL0, cntL1, cntOUT, role, bid, p);
        }
    } else if (bid < 192) {
        // ===== layer 1 (fp8, 2-D tile; deferred own-chain gate mid-phase) =====
        const int q = bid - 64;
        const int bt = q >> 6, rem = q & 63;
        const int cell = 2 + (rem >> 5), jt = rem & 31;
        const int j0 = jt * 16, rb = bt * 128;
        const int j = j0 + lrow;
        int wgbase[4];
        #pragma unroll
        for (int g = 0; g < 4; ++g) wgbase[g] = WOFF + (g * 16 + lrow) * 1536;

        float b1v[4];
        #pragma unroll
        for (int g = 0; g < 4; ++g) b1v[g] = bias1[(size_t)(cell - 2) * FH + g * 512 + j];

        float cv[4];
        #pragma unroll
        for (int r = 0; r < 4; ++r) {
            int bb = rb + wave * 16 + kg * 4 + r;
            cv[r] = c0[((size_t)cell * B + bb) * H + j];
        }

        for (int p = 0; p < NPH; ++p) {
            if (p >= 1 && p <= T) {
                const int pm3 = p % 3;
                const int parY  = (pm3 + 2) % 3;   // step p-1 (cells 0/1)
                const int parR2 = (pm3 + 1) % 3;   // own step p-2
                const int parW  = parY;            // write step p-1
                const u8_t* base0 = hf8 + (size_t)(0 * 3 + parY) * BHs;
                const u8_t* base1 = hf8 + (size_t)(1 * 3 + parY) * BHs;
                const u8_t* base2 = hf8 + (size_t)(cell * 3 + parR2) * BHs;

                f32x4 acc[4];
                #pragma unroll
                for (int g = 0; g < 4; ++g) acc[g] = (f32x4){0.f, 0.f, 0.f, 0.f};

                // ---- segment A: y0 (base0+base1), dep = L0[p-1] (at boundary) ----
                #pragma unroll
                for (int c2 = 0; c2 < 8; ++c2)
                    stageB8(base0, rb, c2 * 64, smem + c2 * 8192, wave, lane);

                #pragma unroll
                for (int t = 0; t < 16; ++t) {
                    LADDER8(15 - t);
                    __builtin_amdgcn_sched_barrier(0);
                    const char* Ab = smem + (t & 7) * 8192;
                    u64_t aA[2], wW[2][4];
                    #pragma unroll
                    for (int ks = 0; ks < 2; ++ks) {
                        aA[ks] = *(const u64_t*)(Ab + aoffB[ks]);
                        #pragma unroll
                        for (int g = 0; g < 4; ++g)
                            wW[ks][g] = *(const u64_t*)(smem + wgbase[g] + t * 64 + wksoff[ks]);
                    }
                    asm volatile("s_waitcnt lgkmcnt(0)" ::: "memory");
                    __builtin_amdgcn_sched_barrier(0);
                    if (t < 8)
                        stageB8(base1, rb, t * 64, smem + (t & 7) * 8192, wave, lane);
                    __builtin_amdgcn_sched_barrier(0);
                    #pragma unroll
                    for (int ks = 0; ks < 2; ++ks)
                        #pragma unroll
                        for (int g = 0; g < 4; ++g)
                            acc[g] = __builtin_amdgcn_mfma_f32_16x16x32_fp8_fp8(
                                (long)aA[ks], (long)wW[ks][g], acc[g], 0, 0, 0);
                }

                // ---- deferred gate: own-chain deps (hidden under segment A) ----
                gateL1(cntL1, cntOUT, p);

                // ---- segment B: own h (base2) ----
                #pragma unroll
                for (int c2 = 0; c2 < 8; ++c2)
                    stageB8(base2, rb, c2 * 64, smem + c2 * 8192, wave, lane);

                #pragma unroll
                for (int tt = 0; tt < 8; ++tt) {
                    const int t = 16 + tt;
                    LADDER8(7 - tt);
                    __builtin_amdgcn_sched_barrier(0);
                    const char* Ab = smem + (tt & 7) * 8192;
                    u64_t aA[2], wW[2][4];
                    #pragma unroll
                    for (int ks = 0; ks < 2; ++ks) {
                        aA[ks] = *(const u64_t*)(Ab + aoffB[ks]);
                        #pragma unroll
                        for (int g = 0; g < 4; ++g)
                            wW[ks][g] = *(const u64_t*)(smem + wgbase[g] + t * 64 + wksoff[ks]);
                    }
                    asm volatile("s_waitcnt lgkmcnt(0)" ::: "memory");
                    __builtin_amdgcn_sched_barrier(0);
                    #pragma unroll
                    for (int ks = 0; ks < 2; ++ks)
                        #pragma unroll
                        for (int g = 0; g < 4; ++g)
                            acc[g] = __builtin_amdgcn_mfma_f32_16x16x32_fp8_fp8(
                                (long)aA[ks], (long)wW[ks][g], acc[g], 0, 0, 0);
                }

                #pragma unroll
                for (int r = 0; r < 4; ++r) {
                    int bb = rb + wave * 16 + kg * 4 + r;
                    float gi = acc[0][r] + b1v[0];
                    float gf = acc[1][r] + b1v[1];
                    float gg = acc[2][r] + b1v[2];
                    float go = acc[3][r] + b1v[3];
                    float ii = sigm(gi), ff = sigm(gf), oo = sigm(go);
                    float tg = tanhf(gg);
                    float cn = ff * cv[r] + ii * tg;
                    cv[r] = cn;
                    float hn = oo * tanhf(cn);
                    size_t hi = ((size_t)(cell * 3 + parW) * B + bb) * H + j;
                    stc1(&hf8[hi], f2fp8(hn));
                    stc2(&hb16[hi], f2b(hn));      // bf16 copy for OUT role
                }
            }
            if (p < NPH - 1) boundary(cntL0, cntL1, cntOUT, role, bid, p);
        }
    } else {
        // ================= logits (bf16 path) =================
        const int b = (bid - 192) * 8 + wave;
        const int c = lane & 31, kh = lane >> 5;
        const int half = lane >> 5, qq = lane & 31;
        const int sww = (c & 7) << 4;
        const int rowbase = c * 2048;
        const int lenb = lens[b];
        const float bo = (c < NC) ? bout[c] : 0.f;
        char* scr = smem + 57344 + wave * 2048;

        for (int p = 0; p < NPH; ++p) {
            if (p >= 2) {
                const int t2 = p - 2;
                const int parL = (p % 3 + 1) % 3;      // step p-2
                {
                    const ushort_t* src = hb16 + (size_t)((2 + half) * 3 + parL) * BHs
                                        + (size_t)b * H + qq * 16;
                    bf16x8 v0 = ldc16(src);
                    bf16x8 v1 = ldc16(src + 8);
                    char* dst = scr + half * 1024 + qq * 32;
                    *(bf16x8*)dst = v0;
                    *(bf16x8*)(dst + 16) = v1;
                }
                __syncthreads();
                float sum = 0.f;
                if (c < NC) {
                    const char* ybase = scr + kh * 1024;
                    #pragma unroll 8
                    for (int t = 0; t < 64; ++t) {
                        bf16x8 v = *(const bf16x8*)(ybase + t * 16);
                        bf16x8 w = *(const bf16x8*)(smem + rowbase + ((kh * 1024 + t * 16) ^ sww));
                        #pragma unroll
                        for (int i = 0; i < 8; ++i) sum += (float)v[i] * (float)w[i];
                    }
                }
                sum += __shfl_xor(sum, 32);
                if (kh == 0 && c < NC) {
                    float val = (t2 < lenb) ? (sum + bo) : 0.f;
                    stc4f(&out[((size_t)b * T + t2) * NC + c], val);
                }
            }
            if (p < NPH - 1) boundary(cntL0, cntL1, cntOUT, role, bid, p);
        }
    }
}

// ---------------- launch ----------------

extern "C" void kernel_launch(void* const* d_in, const int* in_sizes, int n_in,
                              void* d_out, int out_size, void* d_ws, size_t ws_size,
                              hipStream_t stream) {
    const int*   tok   = (const int*)d_in[0];
    const int*   lens  = (const int*)d_in[1];
    const float* h0    = (const float*)d_in[2];
    const float* c0    = (const float*)d_in[3];
    const float* embed = (const float*)d_in[4];
    const float* Wih0  = (const float*)d_in[5];
    const float* Wih1  = (const float*)d_in[6];
    const float* Whh   = (const float*)d_in[7];
    const float* bih   = (const float*)d_in[8];
    const float* bhh   = (const float*)d_in[9];
    const float* Wout  = (const float*)d_in[10];
    const float* bout  = (const float*)d_in[11];
    float* out = (float*)d_out;

    ushort_t* hb16  = (ushort_t*)d_ws;                        // [4][3][B][H] bf16, 3MB
    u8_t*     hf8   = (u8_t*)(hb16 + (size_t)4 * 3 * B * H);  // [4][3][B][H] fp8, 1.5MB
    float*    G0    = (float*)(hf8 + (size_t)4 * 3 * B * H);  // [2][28][512][4] f32
    float*    bias1 = G0 + 2 * NE * FH;                       // [2][2048] f32
    int*      cnt   = (int*)(bias1 + 2 * FH);                 // [3][NPH][CROW]
    int*      tokT  = cnt + 3 * NPH * CROW;                   // [T][B]

    (void)hipFuncSetAttribute((const void*)k_persist,
                              hipFuncAttributeMaxDynamicSharedMemorySize, LDS_BYTES);

    k_init<<<256, 256, 0, stream>>>(cnt);
    k_g0<<<(2 * NE * FH + 255) / 256, 256, 0, stream>>>(embed, Wih0, bih, bhh, G0, bias1);
    k_state<<<(4 * B * H + 255) / 256, 256, 0, stream>>>(h0, hb16, hf8);
    k_tokT<<<(B * T + 255) / 256, 256, 0, stream>>>(tok, tokT);
    k_len<<<1, 256, 0, stream>>>(lens, out + (size_t)B * T * NC);

    k_persist<<<NL0 + NL1 + NOUT, 512, LDS_BYTES, stream>>>(
        Whh, Wih1, G0, bias1, c0, hb16, hf8, tokT, lens, Wout, bout, out, cnt);
}

// Round 19
// 4694.947 us; speedup vs baseline: 1.0265x; 1.0265x over previous
//
#include <hip/hip_runtime.h>
#include <hip/hip_bf16.h>
#include <stdint.h>

typedef unsigned short ushort_t;
typedef unsigned char u8_t;
typedef unsigned long long u64_t;

#define H   512
#define E   128
#define NC  27
#define NE  28
#define B   256
#define T   512
#define FH  2048        // 4*H
#define NPH (T + 2)     // phases 0..T+1
#define NL0 64
#define NL1 128
#define NOUT 32
#define BHs (B * H)
#define WOFF_L0 131072  // L0: ring 8 x 16KB in [0,128K); weights 32KB above
#define WOFF_L1 65536   // L1: ring 8 x 8KB  in [0,64K);  weights 96KB above
#define LDS_BYTES (160 * 1024)
// counters: 16 cells/phase, each on its own 64B line (16-int stride)
#define CROW 256        // ints per role-phase row (16 cells x 16 ints)

typedef __bf16 bf16x8 __attribute__((ext_vector_type(8)));
typedef float  f32x4  __attribute__((ext_vector_type(4)));

#define WAITV(n) asm volatile("s_waitcnt vmcnt(" #n ")" ::: "memory")
#define LADDER8(rem) do { if ((rem) >= 7) WAITV(7); else if ((rem) == 6) WAITV(6); \
                          else if ((rem) == 5) WAITV(5); else if ((rem) == 4) WAITV(4); \
                          else if ((rem) == 3) WAITV(3); else if ((rem) == 2) WAITV(2); \
                          else if ((rem) == 1) WAITV(1); else WAITV(0); } while (0)

__device__ __forceinline__ ushort_t f2b(float x) {
    uint32_t u = __float_as_uint(x);
    uint32_t r = (u + 0x7FFFu + ((u >> 16) & 1u)) >> 16;
    return (ushort_t)r;
}
// f32 -> fp8 e4m3fn, RNE, handles subnormals
__device__ __forceinline__ u8_t f2fp8(float x) {
    uint32_t u = __float_as_uint(x);
    uint32_t s = (u >> 24) & 0x80u;
    int E8 = (int)((u >> 23) & 0xffu);
    uint32_t M = u & 0x7fffffu;
    if (E8 == 0) return (u8_t)s;
    int e8 = E8 - 120;
    uint32_t code;
    if (e8 <= 0) {
        int sh = 1 - e8;
        if (sh > 23) return (u8_t)s;
        code = (0x800000u | M) >> sh;
    } else {
        code = ((uint32_t)e8 << 23) | M;
    }
    uint32_t r = (code + 0x7ffffu + ((code >> 20) & 1u)) >> 20;
    if (r > 0x7eu) r = 0x7eu;
    return (u8_t)(s | r);
}
__device__ __forceinline__ float sigm(float x) {
    return 1.f / (1.f + __expf(-x));
}
__device__ __forceinline__ void stc1(u8_t* p, u8_t v) {
    __hip_atomic_store(p, v, __ATOMIC_RELAXED, __HIP_MEMORY_SCOPE_AGENT);
}
__device__ __forceinline__ void stc2(ushort_t* p, ushort_t v) {
    __hip_atomic_store(p, v, __ATOMIC_RELAXED, __HIP_MEMORY_SCOPE_AGENT);
}
__device__ __forceinline__ void stc4f(float* p, float v) {
    __hip_atomic_store(p, v, __ATOMIC_RELAXED, __HIP_MEMORY_SCOPE_AGENT);
}
__device__ __forceinline__ bf16x8 ldc16(const ushort_t* p) {
    union { u64_t q[2]; bf16x8 v; } u;
    u.q[0] = __hip_atomic_load((const u64_t*)p,       __ATOMIC_RELAXED, __HIP_MEMORY_SCOPE_AGENT);
    u.q[1] = __hip_atomic_load(((const u64_t*)p) + 1, __ATOMIC_RELAXED, __HIP_MEMORY_SCOPE_AGENT);
    return u.v;
}
__device__ __forceinline__ void gload_lds16c(const void* g, void* l) {
    __builtin_amdgcn_global_load_lds(
        (const __attribute__((address_space(1))) void*)g,
        (__attribute__((address_space(3))) void*)l, 16, 0, 17);
}

// L0: stage one fp8 A-chunk [256 rows][64 cols] = 16 KB (wave strip = 32 rows)
__device__ __forceinline__ void stageA8(const u8_t* __restrict__ hsrc, int k0,
                                        char* chunk, int wave, int lane) {
    int gd = lane & 3;
    #pragma unroll
    for (int i = 0; i < 2; ++i) {
        int r = wave * 32 + i * 16 + (lane >> 2);
        int fr = (r & 3) ^ ((r >> 2) & 3);
        const u8_t* g = hsrc + (size_t)r * H + k0 + ((gd ^ fr) << 4);
        gload_lds16c((const void*)g, (void*)(chunk + wave * 2048 + i * 1024));
    }
}

// L1: stage one fp8 A-chunk [128 rows][64 cols] = 8 KB (wave strip = 16 rows)
__device__ __forceinline__ void stageB8(const u8_t* __restrict__ hsrc, int rb, int k0,
                                        char* chunk, int wave, int lane) {
    int r = wave * 16 + (lane >> 2);
    int gd = lane & 3;
    int fr = (r & 3) ^ ((r >> 2) & 3);
    const u8_t* g = hsrc + (size_t)(rb + r) * H + k0 + ((gd ^ fr) << 4);
    gload_lds16c((const void*)g, (void*)(chunk + wave * 1024));
}

// ---------------- setup kernels ----------------

__global__ void k_init(int* __restrict__ cnt) {
    for (int i = blockIdx.x * blockDim.x + threadIdx.x; i < 3 * NPH * CROW;
         i += gridDim.x * blockDim.x) cnt[i] = 0;
}

// G0 layout: [cell][token][j][gate] f32
__global__ void k_g0(const float* __restrict__ embed, const float* __restrict__ Wih0,
                     const float* __restrict__ bih, const float* __restrict__ bhh,
                     float* __restrict__ G0, float* __restrict__ bias1) {
    int i = blockIdx.x * blockDim.x + threadIdx.x;
    if (i < 2 * NE * FH) {
        int d = i / (NE * FH);
        int rem = i % (NE * FH);
        int e = rem / FH;
        int n = rem % FH;
        int g = n >> 9, j = n & 511;
        const float* er = embed + (size_t)e * E;
        const float* wr = Wih0 + ((size_t)d * FH + n) * E;
        float s = 0.f;
        #pragma unroll 8
        for (int k = 0; k < E; ++k) s += er[k] * wr[k];
        G0[(((size_t)d * NE + e) * 512 + j) * 4 + g]
            = s + bih[(size_t)d * FH + n] + bhh[(size_t)d * FH + n];
    }
    if (i < 2 * FH) bias1[i] = bih[2 * FH + i] + bhh[2 * FH + i];
}

// initial h = step -1 -> parity 2
__global__ void k_state(const float* __restrict__ h0, ushort_t* __restrict__ hb16,
                        u8_t* __restrict__ hf8) {
    int i = blockIdx.x * blockDim.x + threadIdx.x;
    if (i >= 4 * B * H) return;
    int cell = i / (B * H);
    int rem  = i % (B * H);
    hb16[((size_t)(cell * 3 + 2)) * BHs + rem] = f2b(h0[i]);
    hf8 [((size_t)(cell * 3 + 2)) * BHs + rem] = f2fp8(h0[i]);
}

__global__ void k_tokT(const int* __restrict__ tok, int* __restrict__ tokT) {
    int i = blockIdx.x * blockDim.x + threadIdx.x;
    if (i < B * T) {
        int b = i / T, t = i % T;
        tokT[(size_t)t * B + b] = tok[i];
    }
}

__global__ void k_len(const int* __restrict__ lens, float* __restrict__ out_len) {
    int i = threadIdx.x;
    if (i < B) out_len[i] = (float)lens[i];
}

// ---------------- decoupled role sync (decontended lines) ----------------
__device__ __forceinline__ int polled(const int* c) {
    int t = 0;
    #pragma unroll
    for (int i = 0; i < 16; ++i)
        t += __hip_atomic_load(c + i * 16, __ATOMIC_RELAXED, __HIP_MEMORY_SCOPE_AGENT);
    return t;
}

// boundary: signal phase p; poll deps of phase q=p+1 needed AT PHASE START.
//   L0(q): L0[q-1], L1[q-2] (write safety)
//   L1(q): L0[q-1] only (y0 stream; own-chain deps deferred to mid-phase gate)
//   OUT(q): L1[q-1]
__device__ __forceinline__ void boundary(int* cntL0, int* cntL1, int* cntOUT,
                                         int role, int bid, int p) {
    __syncthreads();                          // drain this block's vmem (h-stores)
    if (threadIdx.x == 0) {
        int* mine = (role == 0) ? cntL0 : (role == 1) ? cntL1 : cntOUT;
        __hip_atomic_fetch_add(mine + p * CROW + (bid & 15) * 16, 1,
                               __ATOMIC_RELAXED, __HIP_MEMORY_SCOPE_AGENT);
        const int q = p + 1;
        int nl0 = -1, nl1 = -1;
        if (role == 0) {
            if (q < T) {
                nl0 = q - 1;
                if (q >= 2) nl1 = q - 2;
            }
        } else if (role == 1) {
            if (q >= 1 && q <= T) nl0 = q - 1;
        } else {
            if (q >= 2) nl1 = q - 1;
        }
        for (;;) {
            int a = (nl0 >= 0) ? polled(cntL0 + nl0 * CROW) : NL0;
            int b = (nl1 >= 0) ? polled(cntL1 + nl1 * CROW) : NL1;
            if (a >= NL0 && b >= NL1) break;
            __builtin_amdgcn_s_sleep(2);
        }
    }
    __syncthreads();
    __builtin_amdgcn_sched_barrier(0);
}

// deferred L1 gate (mid-phase, after y0 segment): L1[p-1] ∧ OUT[p-2].
// Raw s_barrier: no vmcnt drain (nothing in flight at this point anyway).
__device__ __forceinline__ void gateL1(const int* cntL1, const int* cntOUT, int p) {
    __builtin_amdgcn_sched_barrier(0);
    if (threadIdx.x == 0) {
        for (;;) {
            int a = polled(cntL1 + (p - 1) * CROW);
            int b = (p >= 2) ? polled(cntOUT + (p - 2) * CROW) : NOUT;
            if (a >= NL1 && b >= NOUT) break;
            __builtin_amdgcn_s_sleep(2);
        }
    }
    __builtin_amdgcn_s_barrier();
    __builtin_amdgcn_sched_barrier(0);
}

// Phase p: L0 step t=p (p<T); L1 step s=p-1 (1<=p<=T); OUT logits t2=p-2 (p>=2).
// hf8/hb16: [cell][3][B][H]; step s lives at parity s%3.
__global__ __launch_bounds__(512, 2) void k_persist(
    const float* __restrict__ Whh, const float* __restrict__ Wih1,
    const float* __restrict__ G0, const float* __restrict__ bias1,
    const float* __restrict__ c0, ushort_t* __restrict__ hb16,
    u8_t* __restrict__ hf8,
    const int* __restrict__ tokT, const int* __restrict__ lens,
    const float* __restrict__ Wout, const float* __restrict__ bout,
    float* __restrict__ out, int* __restrict__ cnt)
{
    extern __shared__ char smem[];
    const int bid = blockIdx.x;
    const int tid = threadIdx.x;
    const int lane = tid & 63, wave = tid >> 6;
    const int lrow = lane & 15, kg = lane >> 4;
    const int row0 = wave * 32;
    const int sw8 = lrow & 7;

    int* cntL0  = cnt;
    int* cntL1  = cnt + NPH * CROW;
    int* cntOUT = cnt + 2 * NPH * CROW;
    const int role = (bid < NL0) ? 0 : (bid < NL0 + NL1) ? 1 : 2;

    int wksoff[2];
    #pragma unroll
    for (int ks = 0; ks < 2; ++ks)
        wksoff[ks] = (((ks * 4 + kg) ^ sw8) << 3);

    // ---- one-time: stage weights into LDS (f32 -> fp8, slot-swizzled) ----
    if (bid < 64) {
        const int cell = bid >> 5, jt = bid & 31, j0 = jt * 16;
        const float* Wsrc = Whh + (size_t)cell * FH * H;
        for (int r = wave; r < 64; r += 8) {
            int grow = (r >> 4) * 512 + j0 + (r & 15);
            const float* src = Wsrc + (size_t)grow * H;
            for (int c = lane; c < H; c += 64) {
                int slot = c >> 3;
                int ssw = (slot & ~7) | ((slot ^ r) & 7);
                *(u8_t*)(smem + WOFF_L0 + r * 512 + ssw * 8 + (c & 7)) = f2fp8(src[c]);
            }
        }
    } else if (bid < 192) {
        const int q = bid - 64;
        const int rem = q & 63, cell = 2 + (rem >> 5), jt = rem & 31, j0 = jt * 16;
        const float* Wi = Wih1 + (size_t)(cell - 2) * FH * (2 * H);
        const float* Wh = Whh + (size_t)cell * FH * H;
        for (int r = wave; r < 64; r += 8) {
            int grow = (r >> 4) * 512 + j0 + (r & 15);
            const float* si = Wi + (size_t)grow * (2 * H);
            const float* sh = Wh + (size_t)grow * H;
            for (int c = lane; c < 1536; c += 64) {
                float v = (c < 1024) ? si[c] : sh[c - 1024];
                int slot = c >> 3;
                int ssw = (slot & ~7) | ((slot ^ r) & 7);
                *(u8_t*)(smem + WOFF_L1 + r * 1536 + ssw * 8 + (c & 7)) = f2fp8(v);
            }
        }
    } else {
        for (int r = wave; r < NC; r += 8) {
            const float* src = Wout + (size_t)r * (2 * H);
            int sw = (r & 7) << 4;
            for (int c = lane; c < 2 * H; c += 64) {
                int byte = ((r * (2 * H) + c) * 2) ^ sw;
                *(ushort_t*)(smem + byte) = f2b(src[c]);
            }
        }
    }
    __syncthreads();

    if (bid < 64) {
        // ================= layer 0 (fp8, whole-K staged up-front) =================
        const int cell = bid >> 5, jt = bid & 31, j0 = jt * 16;
        const int j = j0 + lrow;
        const int fA = (lrow & 3) ^ ((lrow >> 2) & 3);
        int aoffK[2];
        #pragma unroll
        for (int ks = 0; ks < 2; ++ks)
            aoffK[ks] = (row0 + lrow) * 64 + ((((ks << 1) | (kg >> 1)) ^ fA) << 4) + ((kg & 1) << 3);
        int wgbase[4];
        #pragma unroll
        for (int g = 0; g < 4; ++g) wgbase[g] = WOFF_L0 + (g * 16 + lrow) * 512;

        float cv[8];
        #pragma unroll
        for (int i = 0; i < 8; ++i) {
            int bb = row0 + (i >> 2) * 16 + kg * 4 + (i & 3);
            cv[i] = c0[((size_t)cell * B + bb) * H + j];
        }
        f32x4 g0v[8];
        #pragma unroll
        for (int i = 0; i < 8; ++i) {
            int bb = row0 + (i >> 2) * 16 + kg * 4 + (i & 3);
            int tk = tokT[bb];
            g0v[i] = *(const f32x4*)(G0 + (((size_t)cell * NE + tk) * 512 + j) * 4);
        }

        for (int p = 0; p < NPH; ++p) {
            if (p < T) {
                const int pm3 = p % 3;
                const int parR = (pm3 + 2) % 3, parW = pm3;
                const u8_t* hsrc = hf8 + (size_t)(cell * 3 + parR) * BHs;

                #pragma unroll
                for (int c2 = 0; c2 < 8; ++c2)
                    stageA8(hsrc, c2 * 64, smem + c2 * 16384, wave, lane);

                f32x4 acc[2][4];
                #pragma unroll
                for (int m = 0; m < 2; ++m)
                    #pragma unroll
                    for (int g = 0; g < 4; ++g) acc[m][g] = (f32x4){0.f, 0.f, 0.f, 0.f};

                #pragma unroll
                for (int t = 0; t < 8; ++t) {
                    if (t == 0)      WAITV(14);
                    else if (t == 1) WAITV(12);
                    else if (t == 2) WAITV(10);
                    else if (t == 3) WAITV(8);
                    else if (t == 4) WAITV(6);
                    else if (t == 5) WAITV(4);
                    else if (t == 6) WAITV(2);
                    else             WAITV(0);
                    __builtin_amdgcn_sched_barrier(0);
                    const char* Ab = smem + t * 16384;
                    u64_t aA[2][2], wW[2][4];
                    #pragma unroll
                    for (int ks = 0; ks < 2; ++ks) {
                        aA[ks][0] = *(const u64_t*)(Ab + aoffK[ks]);
                        aA[ks][1] = *(const u64_t*)(Ab + aoffK[ks] + 1024);
                        #pragma unroll
                        for (int g = 0; g < 4; ++g)
                            wW[ks][g] = *(const u64_t*)(smem + wgbase[g] + t * 64 + wksoff[ks]);
                    }
                    asm volatile("s_waitcnt lgkmcnt(0)" ::: "memory");
                    __builtin_amdgcn_sched_barrier(0);
                    #pragma unroll
                    for (int ks = 0; ks < 2; ++ks)
                        #pragma unroll
                        for (int g = 0; g < 4; ++g) {
                            acc[0][g] = __builtin_amdgcn_mfma_f32_16x16x32_fp8_fp8(
                                (long)aA[ks][0], (long)wW[ks][g], acc[0][g], 0, 0, 0);
                            acc[1][g] = __builtin_amdgcn_mfma_f32_16x16x32_fp8_fp8(
                                (long)aA[ks][1], (long)wW[ks][g], acc[1][g], 0, 0, 0);
                        }
                }

                #pragma unroll
                for (int i = 0; i < 8; ++i) {
                    int mf = i >> 2, r = i & 3;
                    int bb = row0 + mf * 16 + kg * 4 + r;
                    float gi = acc[mf][0][r] + g0v[i][0];
                    float gf = acc[mf][1][r] + g0v[i][1];
                    float gg = acc[mf][2][r] + g0v[i][2];
                    float go = acc[mf][3][r] + g0v[i][3];
                    float ii = sigm(gi), ff = sigm(gf), oo = sigm(go);
                    float tg = tanhf(gg);
                    float cn = ff * cv[i] + ii * tg;
                    cv[i] = cn;
                    float hn = oo * tanhf(cn);
                    stc1(&hf8[((size_t)(cell * 3 + parW) * B + bb) * H + j], f2fp8(hn));
                }
                if (p + 1 < T) {
                    #pragma unroll
                    for (int i = 0; i < 8; ++i) {
                        int bb = row0 + (i >> 2) * 16 + kg * 4 + (i & 3);
                        int tk = tokT[(size_t)(p + 1) * B + bb];
                        g0v[i] = *(const f32x4*)(G0 + (((size_t)cell * NE + tk) * 512 + j) * 4);
                    }
                }
            }
            if (p < NPH - 1) boundary(cntL0, cntL1, cntOUT, role, bid, p);
        }
    } else if (bid < 192) {
        // ===== layer 1 (fp8, 2-D tile; deferred own-chain gate mid-phase) =====
        const int q = bid - 64;
        const int bt = q >> 6, rem = q & 63;
        const int cell = 2 + (rem >> 5), jt = rem & 31;
        const int j0 = jt * 16, rb = bt * 128;
        const int j = j0 + lrow;
        const int fB = (lrow & 3) ^ ((wave * 4 + (lrow >> 2)) & 3);
        int aoffB[2];
        #pragma unroll
        for (int ks = 0; ks < 2; ++ks)
            aoffB[ks] = (wave * 16 + lrow) * 64 + ((((ks << 1) | (kg >> 1)) ^ fB) << 4) + ((kg & 1) << 3);
        int wgbase[4];
        #pragma unroll
        for (int g = 0; g < 4; ++g) wgbase[g] = WOFF_L1 + (g * 16 + lrow) * 1536;

        float b1v[4];
        #pragma unroll
        for (int g = 0; g < 4; ++g) b1v[g] = bias1[(size_t)(cell - 2) * FH + g * 512 + j];

        float cv[4];
        #pragma unroll
        for (int r = 0; r < 4; ++r) {
            int bb = rb + wave * 16 + kg * 4 + r;
            cv[r] = c0[((size_t)cell * B + bb) * H + j];
        }

        for (int p = 0; p < NPH; ++p) {
            if (p >= 1 && p <= T) {
                const int pm3 = p % 3;
                const int parY  = (pm3 + 2) % 3;   // step p-1 (cells 0/1)
                const int parR2 = (pm3 + 1) % 3;   // own step p-2
                const int parW  = parY;            // write step p-1
                const u8_t* base0 = hf8 + (size_t)(0 * 3 + parY) * BHs;
                const u8_t* base1 = hf8 + (size_t)(1 * 3 + parY) * BHs;
                const u8_t* base2 = hf8 + (size_t)(cell * 3 + parR2) * BHs;

                f32x4 acc[4];
                #pragma unroll
                for (int g = 0; g < 4; ++g) acc[g] = (f32x4){0.f, 0.f, 0.f, 0.f};

                // ---- segment A: y0 (base0+base1), dep = L0[p-1] (at boundary) ----
                #pragma unroll
                for (int c2 = 0; c2 < 8; ++c2)
                    stageB8(base0, rb, c2 * 64, smem + c2 * 8192, wave, lane);

                #pragma unroll
                for (int t = 0; t < 16; ++t) {
                    LADDER8(15 - t);
                    __builtin_amdgcn_sched_barrier(0);
                    const char* Ab = smem + (t & 7) * 8192;
                    u64_t aA[2], wW[2][4];
                    #pragma unroll
                    for (int ks = 0; ks < 2; ++ks) {
                        aA[ks] = *(const u64_t*)(Ab + aoffB[ks]);
                        #pragma unroll
                        for (int g = 0; g < 4; ++g)
                            wW[ks][g] = *(const u64_t*)(smem + wgbase[g] + t * 64 + wksoff[ks]);
                    }
                    asm volatile("s_waitcnt lgkmcnt(0)" ::: "memory");
                    __builtin_amdgcn_sched_barrier(0);
                    if (t < 8)
                        stageB8(base1, rb, t * 64, smem + (t & 7) * 8192, wave, lane);
                    __builtin_amdgcn_sched_barrier(0);
                    #pragma unroll
                    for (int ks = 0; ks < 2; ++ks)
                        #pragma unroll
                        for (int g = 0; g < 4; ++g)
                            acc[g] = __builtin_amdgcn_mfma_f32_16x16x32_fp8_fp8(
                                (long)aA[ks], (long)wW[ks][g], acc[g], 0, 0, 0);
                }

                // ---- deferred gate: own-chain deps (hidden under segment A) ----
                gateL1(cntL1, cntOUT, p);

                // ---- segment B: own h (base2) ----
                #pragma unroll
                for (int c2 = 0; c2 < 8; ++c2)
                    stageB8(base2, rb, c2 * 64, smem + c2 * 8192, wave, lane);

                #pragma unroll
                for (int tt = 0; tt < 8; ++tt) {
                    const int t = 16 + tt;
                    LADDER8(7 - tt);
                    __builtin_amdgcn_sched_barrier(0);
                    const char* Ab = smem + (tt & 7) * 8192;
                    u64_t aA[2], wW[2][4];
                    #pragma unroll
                    for (int ks = 0; ks < 2; ++ks) {
                        aA[ks] = *(const u64_t*)(Ab + aoffB[ks]);
                        #pragma unroll
                        for (int g = 0; g < 4; ++g)
                            wW[ks][g] = *(const u64_t*)(smem + wgbase[g] + t * 64 + wksoff[ks]);
                    }
                    asm volatile("s_waitcnt lgkmcnt(0)" ::: "memory");
                    __builtin_amdgcn_sched_barrier(0);
                    #pragma unroll
                    for (int ks = 0; ks < 2; ++ks)
                        #pragma unroll
                        for (int g = 0; g < 4; ++g)
                            acc[g] = __builtin_amdgcn_mfma_f32_16x16x32_fp8_fp8(
                                (long)aA[ks], (long)wW[ks][g], acc[g], 0, 0, 0);
                }

                #pragma unroll
                for (int r = 0; r < 4; ++r) {
                    int bb = rb + wave * 16 + kg * 4 + r;
                    float gi = acc[0][r] + b1v[0];
                    float gf = acc[1][r] + b1v[1];
                    float gg = acc[2][r] + b1v[2];
                    float go = acc[3][r] + b1v[3];
                    float ii = sigm(gi), ff = sigm(gf), oo = sigm(go);
                    float tg = tanhf(gg);
                    float cn = ff * cv[r] + ii * tg;
                    cv[r] = cn;
                    float hn = oo * tanhf(cn);
                    size_t hi = ((size_t)(cell * 3 + parW) * B + bb) * H + j;
                    stc1(&hf8[hi], f2fp8(hn));
                    stc2(&hb16[hi], f2b(hn));      // bf16 copy for OUT role
                }
            }
            if (p < NPH - 1) boundary(cntL0, cntL1, cntOUT, role, bid, p);
        }
    } else {
        // ================= logits (bf16 path) =================
        const int b = (bid - 192) * 8 + wave;
        const int c = lane & 31, kh = lane >> 5;
        const int half = lane >> 5, qq = lane & 31;
        const int sww = (c & 7) << 4;
        const int rowbase = c * 2048;
        const int lenb = lens[b];
        const float bo = (c < NC) ? bout[c] : 0.f;
        char* scr = smem + 57344 + wave * 2048;

        for (int p = 0; p < NPH; ++p) {
            if (p >= 2) {
                const int t2 = p - 2;
                const int parL = (p % 3 + 1) % 3;      // step p-2
                {
                    const ushort_t* src = hb16 + (size_t)((2 + half) * 3 + parL) * BHs
                                        + (size_t)b * H + qq * 16;
                    bf16x8 v0 = ldc16(src);
                    bf16x8 v1 = ldc16(src + 8);
                    char* dst = scr + half * 1024 + qq * 32;
                    *(bf16x8*)dst = v0;
                    *(bf16x8*)(dst + 16) = v1;
                }
                __syncthreads();
                float sum = 0.f;
                if (c < NC) {
                    const char* ybase = scr + kh * 1024;
                    #pragma unroll 8
                    for (int t = 0; t < 64; ++t) {
                        bf16x8 v = *(const bf16x8*)(ybase + t * 16);
                        bf16x8 w = *(const bf16x8*)(smem + rowbase + ((kh * 1024 + t * 16) ^ sww));
                        #pragma unroll
                        for (int i = 0; i < 8; ++i) sum += (float)v[i] * (float)w[i];
                    }
                }
                sum += __shfl_xor(sum, 32);
                if (kh == 0 && c < NC) {
                    float val = (t2 < lenb) ? (sum + bo) : 0.f;
                    stc4f(&out[((size_t)b * T + t2) * NC + c], val);
                }
            }
            if (p < NPH - 1) boundary(cntL0, cntL1, cntOUT, role, bid, p);
        }
    }
}

// ---------------- launch ----------------

extern "C" void kernel_launch(void* const* d_in, const int* in_sizes, int n_in,
                              void* d_out, int out_size, void* d_ws, size_t ws_size,
                              hipStream_t stream) {
    const int*   tok   = (const int*)d_in[0];
    const int*   lens  = (const int*)d_in[1];
    const float* h0    = (const float*)d_in[2];
    const float* c0    = (const float*)d_in[3];
    const float* embed = (const float*)d_in[4];
    const float* Wih0  = (const float*)d_in[5];
    const float* Wih1  = (const float*)d_in[6];
    const float* Whh   = (const float*)d_in[7];
    const float* bih   = (const float*)d_in[8];
    const float* bhh   = (const float*)d_in[9];
    const float* Wout  = (const float*)d_in[10];
    const float* bout  = (const float*)d_in[11];
    float* out = (float*)d_out;

    ushort_t* hb16  = (ushort_t*)d_ws;                        // [4][3][B][H] bf16, 3MB
    u8_t*     hf8   = (u8_t*)(hb16 + (size_t)4 * 3 * B * H);  // [4][3][B][H] fp8, 1.5MB
    float*    G0    = (float*)(hf8 + (size_t)4 * 3 * B * H);  // [2][28][512][4] f32
    float*    bias1 = G0 + 2 * NE * FH;                       // [2][2048] f32
    int*      cnt   = (int*)(bias1 + 2 * FH);                 // [3][NPH][CROW]
    int*      tokT  = cnt + 3 * NPH * CROW;                   // [T][B]

    (void)hipFuncSetAttribute((const void*)k_persist,
                              hipFuncAttributeMaxDynamicSharedMemorySize, LDS_BYTES);

    k_init<<<256, 256, 0, stream>>>(cnt);
    k_g0<<<(2 * NE * FH + 255) / 256, 256, 0, stream>>>(embed, Wih0, bih, bhh, G0, bias1);
    k_state<<<(4 * B * H + 255) / 256, 256, 0, stream>>>(h0, hb16, hf8);
    k_tokT<<<(B * T + 255) / 256, 256, 0, stream>>>(tok, tokT);
    k_len<<<1, 256, 0, stream>>>(lens, out + (size_t)B * T * NC);

    k_persist<<<NL0 + NL1 + NOUT, 512, LDS_BYTES, stream>>>(
        Whh, Wih1, G0, bias1, c0, hb16, hf8, tokT, lens, Wout, bout, out, cnt);
}